// Round 6
// baseline (420.739 us; speedup 1.0000x reference)
//
#include <hip/hip_runtime.h>
#include <cstdint>

#define CCH 512
#define HW  4096
#define WDIM 64
#define NBATCH 8
#define CHW ((size_t)CCH * HW)

typedef __attribute__((ext_vector_type(8))) short bf16x8;
typedef __attribute__((ext_vector_type(4))) float f32x4;
typedef __attribute__((ext_vector_type(4))) unsigned u32x4;

__device__ __forceinline__ unsigned short f2bf(float x) {
  unsigned u = __float_as_uint(x);
  unsigned r = (u + 0x7FFFu + ((u >> 16) & 1u)) >> 16;
  return (unsigned short)r;
}
__device__ __forceinline__ float bf2f(unsigned short h) {
  return __uint_as_float(((unsigned)h) << 16);
}

__device__ __forceinline__ void gl_lds16(const void* g, void* l) {
  __builtin_amdgcn_global_load_lds(
      (const __attribute__((address_space(1))) void*)g,
      (__attribute__((address_space(3))) void*)l, 16, 0, 0);
}

// ---------------------------------------------------------------------------
// P0: split W (fp32 [o][c]) -> bf16 hi/lo (RNE). Whl: [br][hi|lo] ushort.
// ---------------------------------------------------------------------------
__global__ __launch_bounds__(256) void wsplit_k(
    const float* __restrict__ Wo, const float* __restrict__ Wsr,
    unsigned short* __restrict__ Whl) {
  const int br = blockIdx.y;
  const float* W = br ? Wsr : Wo;
  const int i = blockIdx.x * 256 + threadIdx.x;
  const float x = W[i];
  const unsigned short h = f2bf(x);
  unsigned short* dst = Whl + (size_t)br * 524288;
  dst[i] = h;
  dst[262144 + i] = f2bf(x - bf2f(h));
}

// ---------------------------------------------------------------------------
// K1: MFMA GEMM  F[o][p] = sum_c W[o][c] * X[c][p]  (split-bf16 3-product).
// A (W hi/lo): precomputed bf16, DMA-staged, XOR-swizzled k-chunks (0-conflict).
// B (X): raw fp32 32x128 tile DMA-staged with per-row-group column rotation
//   16*(t&1) on the SOURCE address. Phase analysis: LDS services 32-lane
//   phases (quads {0,1} then {2,3}); rotation 16*(quad&1) makes each phase a
//   full bank permutation -> conflict-free b32 fragment reads.
// Fragments built in-register: truncation hi/lo split packed with v_perm
//   (4 perm + 8 and + 8 sub + 4 perm per 8 elems).
// ---------------------------------------------------------------------------
__global__ __launch_bounds__(256, 4) void mfma_conv_k(
    const unsigned short* __restrict__ Whl,
    const float* __restrict__ opt, const float* __restrict__ sar,
    float* __restrict__ F, int b0) {
  const int z = blockIdx.z;
  const int br = z & 1, bl = z >> 1;
  const unsigned short* Ah_g = Whl + (size_t)br * 524288;
  const unsigned short* Al_g = Ah_g + 262144;
  const float* Xb = (br ? sar : opt) + (size_t)(b0 + bl) * CHW;
  const int n0 = blockIdx.x * 128, m0 = blockIdx.y * 128;

  __shared__ unsigned short Ahs[128 * 32];  // 8 KB
  __shared__ unsigned short Als[128 * 32];  // 8 KB
  __shared__ float Xs[32 * 128];            // 16 KB

  const int tid = threadIdx.x;
  const int wave = tid >> 6, lane = tid & 63;
  const int wm = (wave >> 1) * 64, wn = (wave & 1) * 64;

  f32x4 acc[4][4] = {};

  // A staging: row-in-chunk + swizzled source k-chunk
  const int rl = lane >> 2;
  const int kcA = (((lane & 3) ^ ((lane >> 3) & 3)) * 8);

  // B staging: issue t covers rows t*8 + wave*2 + (lane>>5)
  const int brow_off = wave * 2 + (lane >> 5);  // 0..7
  const int bcol = (lane & 31) * 4;             // dest dword col 0..124

  const int fr = lane & 15;
  const int quad = lane >> 4;
  const int khA = ((quad ^ ((lane >> 1) & 3)) * 8);  // A read swizzle
  const int rotq = 16 * (quad & 1);                  // B read rotation

  for (int k0 = 0; k0 < CCH; k0 += 32) {
    __syncthreads();
    // --- A: W hi/lo bf16 via DMA ---
#pragma unroll
    for (int q = 0; q < 2; ++q) {
      const int rbase = wave * 32 + q * 16;
      const int r = rbase + rl;
      gl_lds16(Ah_g + (size_t)(m0 + r) * CCH + k0 + kcA, &Ahs[rbase * 32]);
      gl_lds16(Al_g + (size_t)(m0 + r) * CCH + k0 + kcA, &Als[rbase * 32]);
    }
    // --- B: raw fp32 X tile, source-rotated by row group (16*(t&1)) ---
#pragma unroll
    for (int t = 0; t < 4; ++t) {
      const int row = t * 8 + brow_off;
      const int srccol = (bcol + 128 - 16 * (t & 1)) & 127;
      gl_lds16(&Xb[(size_t)(k0 + row) * HW + n0 + srccol],
               &Xs[t * 1024 + wave * 256]);
    }
    __syncthreads();

    // A fragments
    bf16x8 ah[4], al[4];
#pragma unroll
    for (int i = 0; i < 4; ++i) {
      ah[i] = *(const bf16x8*)&Ahs[(wm + i * 16 + fr) * 32 + khA];
      al[i] = *(const bf16x8*)&Als[(wm + i * 16 + fr) * 32 + khA];
    }

#pragma unroll
    for (int j = 0; j < 4; ++j) {
      // B fragment pair for column n = wn + j*16 + fr
      const int colj = (wn + j * 16 + fr + rotq) & 127;
      float xv[8];
#pragma unroll
      for (int s = 0; s < 8; ++s) xv[s] = Xs[(quad * 8 + s) * 128 + colj];
      u32x4 hu, lu;
#pragma unroll
      for (int k = 0; k < 4; ++k) {
        const unsigned u0 = __float_as_uint(xv[2 * k]);
        const unsigned u1 = __float_as_uint(xv[2 * k + 1]);
        hu[k] = __builtin_amdgcn_perm(u1, u0, 0x07060302u);
        const float l0 = xv[2 * k] - __uint_as_float(u0 & 0xFFFF0000u);
        const float l1 = xv[2 * k + 1] - __uint_as_float(u1 & 0xFFFF0000u);
        lu[k] = __builtin_amdgcn_perm(__float_as_uint(l1), __float_as_uint(l0),
                                      0x07060302u);
      }
      const bf16x8 bh = __builtin_bit_cast(bf16x8, hu);
      const bf16x8 bl = __builtin_bit_cast(bf16x8, lu);
#pragma unroll
      for (int i = 0; i < 4; ++i) {
        acc[i][j] = __builtin_amdgcn_mfma_f32_16x16x32_bf16(ah[i], bh, acc[i][j], 0, 0, 0);
        acc[i][j] = __builtin_amdgcn_mfma_f32_16x16x32_bf16(ah[i], bl, acc[i][j], 0, 0, 0);
        acc[i][j] = __builtin_amdgcn_mfma_f32_16x16x32_bf16(al[i], bh, acc[i][j], 0, 0, 0);
      }
    }
  }

  float* Fb = F + (size_t)z * CHW;
  const int col = lane & 15, rq = (lane >> 4) * 4;
#pragma unroll
  for (int i = 0; i < 4; ++i)
#pragma unroll
    for (int j = 0; j < 4; ++j) {
      const int n = n0 + wn + j * 16 + col;
#pragma unroll
      for (int r = 0; r < 4; ++r) {
        const int m = m0 + wm + i * 16 + rq + r;
        Fb[(size_t)m * HW + n] = acc[i][j][r];
      }
    }
}

// ---------------------------------------------------------------------------
// K2: S = F^T F per (z,c) via split-bf16 MFMA; padded LDS (conflict-free).
// ---------------------------------------------------------------------------
#define FT_S 72
__global__ __launch_bounds__(256, 4) void gram_k(
    const float* __restrict__ F, float* __restrict__ S) {
  const size_t base = ((size_t)blockIdx.y * CCH + blockIdx.x) * HW;
  const float* Fc = F + base;
  float* Sc = S + base;

  __shared__ float Fs[64][68];
  __shared__ unsigned short FtH[64 * FT_S];
  __shared__ unsigned short FtL[64 * FT_S];

  const int tid = threadIdx.x;

  {
    const int h = tid >> 2;
    const int w0 = (tid & 3) * 16;
    const float* src = &Fc[h * 64 + w0];
    float4 v0 = *(const float4*)(src + 0);
    float4 v1 = *(const float4*)(src + 4);
    float4 v2 = *(const float4*)(src + 8);
    float4 v3 = *(const float4*)(src + 12);
    *(float4*)&Fs[h][w0 + 0]  = v0;
    *(float4*)&Fs[h][w0 + 4]  = v1;
    *(float4*)&Fs[h][w0 + 8]  = v2;
    *(float4*)&Fs[h][w0 + 12] = v3;
  }
  __syncthreads();

  {
    const int w = tid & 63;
    const int hc = (tid >> 6) * 16;
    unsigned short hb[16], lb[16];
#pragma unroll
    for (int k = 0; k < 16; ++k) {
      const float x = Fs[hc + k][w];
      const unsigned short h = f2bf(x);
      hb[k] = h;
      lb[k] = f2bf(x - bf2f(h));
    }
    unsigned short* dh = &FtH[w * FT_S + hc];
    unsigned short* dl = &FtL[w * FT_S + hc];
    *(uint4*)(dh + 0) = *(uint4*)&hb[0];
    *(uint4*)(dh + 8) = *(uint4*)&hb[8];
    *(uint4*)(dl + 0) = *(uint4*)&lb[0];
    *(uint4*)(dl + 8) = *(uint4*)&lb[8];
  }
  __syncthreads();

  const int wave = tid >> 6, lane = tid & 63;
  const int wm = (wave >> 1) * 32, wn = (wave & 1) * 32;
  const int fr = lane & 15, kq = (lane >> 4) * 8;

  f32x4 acc[2][2] = {};
#pragma unroll
  for (int kcc = 0; kcc < 2; ++kcc) {
    bf16x8 ah[2], al[2], bh[2], bl[2];
#pragma unroll
    for (int i = 0; i < 2; ++i) {
      ah[i] = *(const bf16x8*)&FtH[(wm + i * 16 + fr) * FT_S + kcc * 32 + kq];
      al[i] = *(const bf16x8*)&FtL[(wm + i * 16 + fr) * FT_S + kcc * 32 + kq];
      bh[i] = *(const bf16x8*)&FtH[(wn + i * 16 + fr) * FT_S + kcc * 32 + kq];
      bl[i] = *(const bf16x8*)&FtL[(wn + i * 16 + fr) * FT_S + kcc * 32 + kq];
    }
#pragma unroll
    for (int i = 0; i < 2; ++i)
#pragma unroll
      for (int j = 0; j < 2; ++j) {
        acc[i][j] = __builtin_amdgcn_mfma_f32_16x16x32_bf16(ah[i], bh[j], acc[i][j], 0, 0, 0);
        acc[i][j] = __builtin_amdgcn_mfma_f32_16x16x32_bf16(ah[i], bl[j], acc[i][j], 0, 0, 0);
        acc[i][j] = __builtin_amdgcn_mfma_f32_16x16x32_bf16(al[i], bh[j], acc[i][j], 0, 0, 0);
      }
  }

  const int rq = (lane >> 4) * 4;
#pragma unroll
  for (int i = 0; i < 2; ++i)
#pragma unroll
    for (int j = 0; j < 2; ++j) {
      const int n = wn + j * 16 + fr;
#pragma unroll
      for (int r = 0; r < 4; ++r) {
        const int m = wm + i * 16 + rq + r;
        Sc[m * 64 + n] = acc[i][j][r];
      }
    }
}

// ---------------------------------------------------------------------------
// K3: softmax over c (both branches) + hadamard + output.
// 1024 thr/block = 64 c-groups x 16 j-lanes (x4 j). 2 blocks/CU.
// ---------------------------------------------------------------------------
__global__ __launch_bounds__(1024, 8) void softmax_fuse_k(
    const float* __restrict__ S, const float* __restrict__ Fbuf,
    float* __restrict__ Out) {
  const int i = blockIdx.x;   // 0..63
  const int b = blockIdx.y;
  const int tid = threadIdx.x;
  const int jl = (tid & 15) * 4;
  const int g = tid >> 4;     // 0..63 (8 c's each)

  const size_t rowO = (size_t)(b * 2) * CHW + (size_t)i * WDIM;
  const size_t rowS = rowO + CHW;

  float mo[4], lo[4], ms[4], ls[4];
#pragma unroll
  for (int k = 0; k < 4; ++k) { mo[k] = -1e30f; lo[k] = 0.f; ms[k] = -1e30f; ls[k] = 0.f; }

#pragma unroll
  for (int cc = 0; cc < 8; ++cc) {
    const int c = g * 8 + cc;
    const size_t off = (size_t)c * HW + jl;
    float4 xo = *(const float4*)&S[rowO + off];
    float4 xs = *(const float4*)&S[rowS + off];
    float xov[4] = {xo.x, xo.y, xo.z, xo.w};
    float xsv[4] = {xs.x, xs.y, xs.z, xs.w};
#pragma unroll
    for (int k = 0; k < 4; ++k) {
      float nm = fmaxf(mo[k], xov[k]);
      lo[k] = lo[k] * __expf(mo[k] - nm) + __expf(xov[k] - nm);
      mo[k] = nm;
      nm = fmaxf(ms[k], xsv[k]);
      ls[k] = ls[k] * __expf(ms[k] - nm) + __expf(xsv[k] - nm);
      ms[k] = nm;
    }
  }

  __shared__ float sm[2][64][64];
  __shared__ float sl[2][64][64];
  __shared__ float Mf[2][64];
  __shared__ float Li[2][64];

  *(float4*)&sm[0][g][jl] = make_float4(mo[0], mo[1], mo[2], mo[3]);
  *(float4*)&sl[0][g][jl] = make_float4(lo[0], lo[1], lo[2], lo[3]);
  *(float4*)&sm[1][g][jl] = make_float4(ms[0], ms[1], ms[2], ms[3]);
  *(float4*)&sl[1][g][jl] = make_float4(ls[0], ls[1], ls[2], ls[3]);
  __syncthreads();

  if (tid < 128) {
    const int br = tid >> 6, j = tid & 63;
    float M = -1e30f;
#pragma unroll 16
    for (int t = 0; t < 64; ++t) M = fmaxf(M, sm[br][t][j]);
    float L = 0.f;
#pragma unroll 16
    for (int t = 0; t < 64; ++t) L += sl[br][t][j] * __expf(sm[br][t][j] - M);
    Mf[br][j] = M;
    Li[br][j] = 1.f / L;
  }
  __syncthreads();

  float4 Mo4 = *(const float4*)&Mf[0][jl];
  float4 iLo4 = *(const float4*)&Li[0][jl];
  float4 Ms4 = *(const float4*)&Mf[1][jl];
  float4 iLs4 = *(const float4*)&Li[1][jl];
  float Mov[4] = {Mo4.x, Mo4.y, Mo4.z, Mo4.w};
  float iLov[4] = {iLo4.x, iLo4.y, iLo4.z, iLo4.w};
  float Msv[4] = {Ms4.x, Ms4.y, Ms4.z, Ms4.w};
  float iLsv[4] = {iLs4.x, iLs4.y, iLs4.z, iLs4.w};

#pragma unroll
  for (int cc = 0; cc < 8; ++cc) {
    const int c = g * 8 + cc;
    const size_t off = (size_t)c * HW + jl;
    float4 xo = *(const float4*)&S[rowO + off];
    float4 xs = *(const float4*)&S[rowS + off];
    float4 fo = *(const float4*)&Fbuf[rowO + off];
    float4 fs = *(const float4*)&Fbuf[rowS + off];
    float xov[4] = {xo.x, xo.y, xo.z, xo.w};
    float xsv[4] = {xs.x, xs.y, xs.z, xs.w};
    float fov[4] = {fo.x, fo.y, fo.z, fo.w};
    float fsv[4] = {fs.x, fs.y, fs.z, fs.w};
    float ov[4];
#pragma unroll
    for (int k = 0; k < 4; ++k) {
      const float ho = __expf(xov[k] - Mov[k]) * iLov[k];
      const float hs = __expf(xsv[k] - Msv[k]) * iLsv[k];
      float h2 = ho * hs;
      h2 *= h2;
      ov[k] = fov[k] * fsv[k] * h2;
    }
    *(float4*)&Out[(size_t)b * CHW + (size_t)c * HW + (size_t)i * WDIM + jl] =
        make_float4(ov[0], ov[1], ov[2], ov[3]);
  }
}

// ---------------------------------------------------------------------------
extern "C" void kernel_launch(void* const* d_in, const int* in_sizes, int n_in,
                              void* d_out, int out_size, void* d_ws, size_t ws_size,
                              hipStream_t stream) {
  const float* opt = (const float*)d_in[0];
  const float* sar = (const float*)d_in[1];
  const float* Wo  = (const float*)d_in[2];
  const float* Wsr = (const float*)d_in[3];
  float* out = (float*)d_out;

  // workspace: Whl | F | S
  unsigned short* Whl = (unsigned short*)d_ws;
  const size_t whlElems = 2u * 2u * 262144u;     // 2 MB
  const size_t perBl = 2 * CHW;                  // elems per batch (both br)
  const size_t perBlBytes = perBl * 8;           // F(4) + S(4)
  int bc = (int)((ws_size - whlElems * 2) / perBlBytes);
  if (bc < 1) bc = 1;
  if (bc > NBATCH) bc = NBATCH;
  const int passes = (NBATCH + bc - 1) / bc;
  const int nbp = (NBATCH + passes - 1) / passes;

  float* Fbuf = (float*)(Whl + whlElems);
  float* Sbuf = Fbuf + (size_t)bc * perBl;

  hipLaunchKernelGGL(wsplit_k, dim3(1024, 2), dim3(256), 0, stream, Wo, Wsr, Whl);

  for (int b0 = 0; b0 < NBATCH; b0 += nbp) {
    const int nb = (NBATCH - b0 < nbp) ? (NBATCH - b0) : nbp;

    hipLaunchKernelGGL(mfma_conv_k, dim3(32, 4, nb * 2), dim3(256), 0, stream,
                       Whl, opt, sar, Fbuf, b0);

    hipLaunchKernelGGL(gram_k, dim3(CCH, nb * 2), dim3(256), 0, stream,
                       Fbuf, Sbuf);

    hipLaunchKernelGGL(softmax_fuse_k, dim3(WDIM, nb), dim3(1024), 0, stream,
                       Sbuf, Fbuf, out + (size_t)b0 * CHW);
  }
}

// Round 7
// 358.744 us; speedup vs baseline: 1.1728x; 1.1728x over previous
//
#include <hip/hip_runtime.h>
#include <cstdint>

#define CCH 512
#define HW  4096
#define WDIM 64
#define NBATCH 8
#define CHW ((size_t)CCH * HW)

typedef __attribute__((ext_vector_type(8))) short bf16x8;
typedef __attribute__((ext_vector_type(4))) float f32x4;

__device__ __forceinline__ unsigned short f2bf(float x) {
  unsigned u = __float_as_uint(x);
  unsigned r = (u + 0x7FFFu + ((u >> 16) & 1u)) >> 16;
  return (unsigned short)r;
}
__device__ __forceinline__ float bf2f(unsigned short h) {
  return __uint_as_float(((unsigned)h) << 16);
}

__device__ __forceinline__ void gl_lds16(const void* g, void* l) {
  __builtin_amdgcn_global_load_lds(
      (const __attribute__((address_space(1))) void*)g,
      (__attribute__((address_space(3))) void*)l, 16, 0, 0);
}

// ---------------------------------------------------------------------------
// P0: split W (fp32 [o][c]) -> bf16 hi/lo (RNE). Whl: [br][hi|lo] ushort.
// ---------------------------------------------------------------------------
__global__ __launch_bounds__(256) void wsplit_k(
    const float* __restrict__ Wo, const float* __restrict__ Wsr,
    unsigned short* __restrict__ Whl) {
  const int br = blockIdx.y;
  const float* W = br ? Wsr : Wo;
  const int i = blockIdx.x * 256 + threadIdx.x;
  const float x = W[i];
  const unsigned short h = f2bf(x);
  unsigned short* dst = Whl + (size_t)br * 524288;
  dst[i] = h;
  dst[262144 + i] = f2bf(x - bf2f(h));
}

// ---------------------------------------------------------------------------
// K1: MFMA GEMM  F[o][p] = sum_c W[o][c] * X[c][p]  (split-bf16 3-product).
// EXACT round-5 version (measured 81.5 us/dispatch). Round-6's 16*(t&1)
// staging rotation regressed despite zero conflicts — reverted.
// ---------------------------------------------------------------------------
__global__ __launch_bounds__(256, 4) void mfma_conv_k(
    const unsigned short* __restrict__ Whl,
    const float* __restrict__ opt, const float* __restrict__ sar,
    float* __restrict__ F, int b0) {
  const int z = blockIdx.z;
  const int br = z & 1, bl = z >> 1;
  const unsigned short* Ah_g = Whl + (size_t)br * 524288;
  const unsigned short* Al_g = Ah_g + 262144;
  const float* Xb = (br ? sar : opt) + (size_t)(b0 + bl) * CHW;
  const int n0 = blockIdx.x * 128, m0 = blockIdx.y * 128;

  __shared__ unsigned short Ahs[128 * 32];  // 8 KB
  __shared__ unsigned short Als[128 * 32];  // 8 KB
  __shared__ float Xs[32 * 128];            // 16 KB

  const int tid = threadIdx.x;
  const int wave = tid >> 6, lane = tid & 63;
  const int wm = (wave >> 1) * 64, wn = (wave & 1) * 64;

  f32x4 acc[4][4] = {};

  const int rl = lane >> 2;
  const int kcA = (((lane & 3) ^ ((lane >> 3) & 3)) * 8);

  const int brow_off = wave * 2 + (lane >> 5);  // 0..7
  const int bcol = (lane & 31) * 4;             // dest dword col

  const int fr = lane & 15;
  const int quad = lane >> 4;
  const int khA = ((quad ^ ((lane >> 1) & 3)) * 8);

  for (int k0 = 0; k0 < CCH; k0 += 32) {
    __syncthreads();
#pragma unroll
    for (int q = 0; q < 2; ++q) {
      const int rbase = wave * 32 + q * 16;
      const int r = rbase + rl;
      gl_lds16(Ah_g + (size_t)(m0 + r) * CCH + k0 + kcA, &Ahs[rbase * 32]);
      gl_lds16(Al_g + (size_t)(m0 + r) * CCH + k0 + kcA, &Als[rbase * 32]);
    }
#pragma unroll
    for (int t = 0; t < 4; ++t) {
      const int row = t * 8 + brow_off;
      const int srccol = (bcol + 128 - 8 * t) & 127;
      gl_lds16(&Xb[(size_t)(k0 + row) * HW + n0 + srccol],
               &Xs[t * 1024 + wave * 256]);
    }
    __syncthreads();

    bf16x8 ah[4], al[4];
#pragma unroll
    for (int i = 0; i < 4; ++i) {
      ah[i] = *(const bf16x8*)&Ahs[(wm + i * 16 + fr) * 32 + khA];
      al[i] = *(const bf16x8*)&Als[(wm + i * 16 + fr) * 32 + khA];
    }

#pragma unroll
    for (int j = 0; j < 4; ++j) {
      const int colj = (wn + j * 16 + fr + 8 * quad) & 127;
      unsigned short hs[8], ls[8];
#pragma unroll
      for (int s = 0; s < 8; ++s) {
        const float x = Xs[(quad * 8 + s) * 128 + colj];
        const unsigned xu = __float_as_uint(x);
        const float hi = __uint_as_float(xu & 0xFFFF0000u);
        const float lof = x - hi;
        hs[s] = (unsigned short)(xu >> 16);
        ls[s] = (unsigned short)(__float_as_uint(lof) >> 16);
      }
      const bf16x8 bh = *(const bf16x8*)hs;
      const bf16x8 bl = *(const bf16x8*)ls;
#pragma unroll
      for (int i = 0; i < 4; ++i) {
        acc[i][j] = __builtin_amdgcn_mfma_f32_16x16x32_bf16(ah[i], bh, acc[i][j], 0, 0, 0);
        acc[i][j] = __builtin_amdgcn_mfma_f32_16x16x32_bf16(ah[i], bl, acc[i][j], 0, 0, 0);
        acc[i][j] = __builtin_amdgcn_mfma_f32_16x16x32_bf16(al[i], bh, acc[i][j], 0, 0, 0);
      }
    }
  }

  float* Fb = F + (size_t)z * CHW;
  const int col = lane & 15, rq = (lane >> 4) * 4;
#pragma unroll
  for (int i = 0; i < 4; ++i)
#pragma unroll
    for (int j = 0; j < 4; ++j) {
      const int n = n0 + wn + j * 16 + col;
#pragma unroll
      for (int r = 0; r < 4; ++r) {
        const int m = m0 + wm + i * 16 + rq + r;
        Fb[(size_t)m * HW + n] = acc[i][j][r];
      }
    }
}

// ---------------------------------------------------------------------------
// K2 v3: S = F^T F per (z,c) via split-bf16 MFMA.
// F tile staged via gl_lds16 DMA (16 KB contiguous, unpadded [64][64] —
// column reads across 64 lanes are 2-way bank-aliased = free per m136).
// ---------------------------------------------------------------------------
#define FT_S 72
__global__ __launch_bounds__(256, 4) void gram_k(
    const float* __restrict__ F, float* __restrict__ S) {
  const size_t base = ((size_t)blockIdx.y * CCH + blockIdx.x) * HW;
  const float* Fc = F + base;
  float* Sc = S + base;

  __shared__ float Fs[64 * 64];                // 16 KB, unpadded
  __shared__ unsigned short FtH[64 * FT_S];    // 9216 B
  __shared__ unsigned short FtL[64 * FT_S];    // 9216 B

  const int tid = threadIdx.x;
  const int wave = tid >> 6, lane = tid & 63;

  // DMA-stage the whole 16 KB tile: 4 issues x 4 waves x 64 lanes x 16 B
#pragma unroll
  for (int t = 0; t < 4; ++t) {
    const int off = (wave * 4 + t) * 256;
    gl_lds16(Fc + off + lane * 4, &Fs[off]);
  }
  __syncthreads();

  // transpose + split: w = lane, h-chunk = wave*16
  {
    const int w = lane;
    const int hc = wave * 16;
    unsigned short hb[16], lb[16];
#pragma unroll
    for (int k = 0; k < 16; ++k) {
      const float x = Fs[(hc + k) * 64 + w];
      const unsigned short h = f2bf(x);
      hb[k] = h;
      lb[k] = f2bf(x - bf2f(h));
    }
    unsigned short* dh = &FtH[w * FT_S + hc];
    unsigned short* dl = &FtL[w * FT_S + hc];
    *(uint4*)(dh + 0) = *(uint4*)&hb[0];
    *(uint4*)(dh + 8) = *(uint4*)&hb[8];
    *(uint4*)(dl + 0) = *(uint4*)&lb[0];
    *(uint4*)(dl + 8) = *(uint4*)&lb[8];
  }
  __syncthreads();

  const int wm = (wave >> 1) * 32, wn = (wave & 1) * 32;
  const int fr = lane & 15, kq = (lane >> 4) * 8;

  f32x4 acc[2][2] = {};
#pragma unroll
  for (int kcc = 0; kcc < 2; ++kcc) {
    bf16x8 ah[2], al[2], bh[2], bl[2];
#pragma unroll
    for (int i = 0; i < 2; ++i) {
      ah[i] = *(const bf16x8*)&FtH[(wm + i * 16 + fr) * FT_S + kcc * 32 + kq];
      al[i] = *(const bf16x8*)&FtL[(wm + i * 16 + fr) * FT_S + kcc * 32 + kq];
      bh[i] = *(const bf16x8*)&FtH[(wn + i * 16 + fr) * FT_S + kcc * 32 + kq];
      bl[i] = *(const bf16x8*)&FtL[(wn + i * 16 + fr) * FT_S + kcc * 32 + kq];
    }
#pragma unroll
    for (int i = 0; i < 2; ++i)
#pragma unroll
      for (int j = 0; j < 2; ++j) {
        acc[i][j] = __builtin_amdgcn_mfma_f32_16x16x32_bf16(ah[i], bh[j], acc[i][j], 0, 0, 0);
        acc[i][j] = __builtin_amdgcn_mfma_f32_16x16x32_bf16(ah[i], bl[j], acc[i][j], 0, 0, 0);
        acc[i][j] = __builtin_amdgcn_mfma_f32_16x16x32_bf16(al[i], bh[j], acc[i][j], 0, 0, 0);
      }
  }

  const int rq = (lane >> 4) * 4;
#pragma unroll
  for (int i = 0; i < 2; ++i)
#pragma unroll
    for (int j = 0; j < 2; ++j) {
      const int n = wn + j * 16 + fr;
#pragma unroll
      for (int r = 0; r < 4; ++r) {
        const int m = wm + i * 16 + rq + r;
        Sc[m * 64 + n] = acc[i][j][r];
      }
    }
}

// ---------------------------------------------------------------------------
// K3 v4: softmax over c (both branches) + hadamard + output.
// 1024 thr = 64 c-groups x 16 j-lanes (x4 j). S slices cached in registers
// (read S ONCE); max-then-sum over cached values; LDS merge of partials.
// ---------------------------------------------------------------------------
__global__ __launch_bounds__(1024, 4) void softmax_fuse_k(
    const float* __restrict__ S, const float* __restrict__ Fbuf,
    float* __restrict__ Out) {
  const int i = blockIdx.x;   // 0..63
  const int b = blockIdx.y;
  const int tid = threadIdx.x;
  const int jl = (tid & 15) * 4;
  const int g = tid >> 4;     // 0..63 (8 c's each)

  const size_t rowO = (size_t)(b * 2) * CHW + (size_t)i * WDIM;
  const size_t rowS = rowO + CHW;

  float4 xoc[8], xsc[8];
  float mo[4], lo[4], ms[4], ls[4];
#pragma unroll
  for (int k = 0; k < 4; ++k) { mo[k] = -1e30f; ms[k] = -1e30f; lo[k] = 0.f; ls[k] = 0.f; }

  // single pass over S: cache + local max
#pragma unroll
  for (int cc = 0; cc < 8; ++cc) {
    const int c = g * 8 + cc;
    const size_t off = (size_t)c * HW + jl;
    xoc[cc] = *(const float4*)&S[rowO + off];
    xsc[cc] = *(const float4*)&S[rowS + off];
    mo[0] = fmaxf(mo[0], xoc[cc].x); mo[1] = fmaxf(mo[1], xoc[cc].y);
    mo[2] = fmaxf(mo[2], xoc[cc].z); mo[3] = fmaxf(mo[3], xoc[cc].w);
    ms[0] = fmaxf(ms[0], xsc[cc].x); ms[1] = fmaxf(ms[1], xsc[cc].y);
    ms[2] = fmaxf(ms[2], xsc[cc].z); ms[3] = fmaxf(ms[3], xsc[cc].w);
  }
  // local exp-sums vs local max
#pragma unroll
  for (int cc = 0; cc < 8; ++cc) {
    lo[0] += __expf(xoc[cc].x - mo[0]); lo[1] += __expf(xoc[cc].y - mo[1]);
    lo[2] += __expf(xoc[cc].z - mo[2]); lo[3] += __expf(xoc[cc].w - mo[3]);
    ls[0] += __expf(xsc[cc].x - ms[0]); ls[1] += __expf(xsc[cc].y - ms[1]);
    ls[2] += __expf(xsc[cc].z - ms[2]); ls[3] += __expf(xsc[cc].w - ms[3]);
  }

  __shared__ float sm[2][64][64];
  __shared__ float sl[2][64][64];
  __shared__ float Mf[2][64];
  __shared__ float Li[2][64];

  *(float4*)&sm[0][g][jl] = make_float4(mo[0], mo[1], mo[2], mo[3]);
  *(float4*)&sl[0][g][jl] = make_float4(lo[0], lo[1], lo[2], lo[3]);
  *(float4*)&sm[1][g][jl] = make_float4(ms[0], ms[1], ms[2], ms[3]);
  *(float4*)&sl[1][g][jl] = make_float4(ls[0], ls[1], ls[2], ls[3]);
  __syncthreads();

  if (tid < 128) {
    const int br = tid >> 6, j = tid & 63;
    float M = -1e30f;
#pragma unroll 16
    for (int t = 0; t < 64; ++t) M = fmaxf(M, sm[br][t][j]);
    float L = 0.f;
#pragma unroll 16
    for (int t = 0; t < 64; ++t) L += sl[br][t][j] * __expf(sm[br][t][j] - M);
    Mf[br][j] = M;
    Li[br][j] = 1.f / L;
  }
  __syncthreads();

  float4 Mo4 = *(const float4*)&Mf[0][jl];
  float4 iLo4 = *(const float4*)&Li[0][jl];
  float4 Ms4 = *(const float4*)&Mf[1][jl];
  float4 iLs4 = *(const float4*)&Li[1][jl];
  float Mov[4] = {Mo4.x, Mo4.y, Mo4.z, Mo4.w};
  float iLov[4] = {iLo4.x, iLo4.y, iLo4.z, iLo4.w};
  float Msv[4] = {Ms4.x, Ms4.y, Ms4.z, Ms4.w};
  float iLsv[4] = {iLs4.x, iLs4.y, iLs4.z, iLs4.w};

#pragma unroll
  for (int cc = 0; cc < 8; ++cc) {
    const int c = g * 8 + cc;
    const size_t off = (size_t)c * HW + jl;
    float4 fo = *(const float4*)&Fbuf[rowO + off];
    float4 fs = *(const float4*)&Fbuf[rowS + off];
    float xov[4] = {xoc[cc].x, xoc[cc].y, xoc[cc].z, xoc[cc].w};
    float xsv[4] = {xsc[cc].x, xsc[cc].y, xsc[cc].z, xsc[cc].w};
    float fov[4] = {fo.x, fo.y, fo.z, fo.w};
    float fsv[4] = {fs.x, fs.y, fs.z, fs.w};
    float ov[4];
#pragma unroll
    for (int k = 0; k < 4; ++k) {
      const float ho = __expf(xov[k] - Mov[k]) * iLov[k];
      const float hs = __expf(xsv[k] - Msv[k]) * iLsv[k];
      float h2 = ho * hs;
      h2 *= h2;
      ov[k] = fov[k] * fsv[k] * h2;
    }
    *(float4*)&Out[(size_t)b * CHW + (size_t)c * HW + (size_t)i * WDIM + jl] =
        make_float4(ov[0], ov[1], ov[2], ov[3]);
  }
}

// ---------------------------------------------------------------------------
extern "C" void kernel_launch(void* const* d_in, const int* in_sizes, int n_in,
                              void* d_out, int out_size, void* d_ws, size_t ws_size,
                              hipStream_t stream) {
  const float* opt = (const float*)d_in[0];
  const float* sar = (const float*)d_in[1];
  const float* Wo  = (const float*)d_in[2];
  const float* Wsr = (const float*)d_in[3];
  float* out = (float*)d_out;

  // workspace: Whl | F | S
  unsigned short* Whl = (unsigned short*)d_ws;
  const size_t whlElems = 2u * 2u * 262144u;     // 2 MB
  const size_t perBl = 2 * CHW;                  // elems per batch (both br)
  const size_t perBlBytes = perBl * 8;           // F(4) + S(4)
  int bc = (int)((ws_size - whlElems * 2) / perBlBytes);
  if (bc < 1) bc = 1;
  if (bc > NBATCH) bc = NBATCH;
  const int passes = (NBATCH + bc - 1) / bc;
  const int nbp = (NBATCH + passes - 1) / passes;

  float* Fbuf = (float*)(Whl + whlElems);
  float* Sbuf = Fbuf + (size_t)bc * perBl;

  hipLaunchKernelGGL(wsplit_k, dim3(1024, 2), dim3(256), 0, stream, Wo, Wsr, Whl);

  for (int b0 = 0; b0 < NBATCH; b0 += nbp) {
    const int nb = (NBATCH - b0 < nbp) ? (NBATCH - b0) : nbp;

    hipLaunchKernelGGL(mfma_conv_k, dim3(32, 4, nb * 2), dim3(256), 0, stream,
                       Whl, opt, sar, Fbuf, b0);

    hipLaunchKernelGGL(gram_k, dim3(CCH, nb * 2), dim3(256), 0, stream,
                       Fbuf, Sbuf);

    hipLaunchKernelGGL(softmax_fuse_k, dim3(WDIM, nb), dim3(1024), 0, stream,
                       Sbuf, Fbuf, out + (size_t)b0 * CHW);
  }
}

// Round 8
// 352.813 us; speedup vs baseline: 1.1925x; 1.0168x over previous
//
#include <hip/hip_runtime.h>
#include <cstdint>

#define CCH 512
#define HW  4096
#define WDIM 64
#define NBATCH 8
#define CHW ((size_t)CCH * HW)

typedef __attribute__((ext_vector_type(8))) short bf16x8;
typedef __attribute__((ext_vector_type(4))) float f32x4;
typedef __attribute__((ext_vector_type(4))) unsigned u32x4;

__device__ __forceinline__ unsigned short f2bf(float x) {
  unsigned u = __float_as_uint(x);
  unsigned r = (u + 0x7FFFu + ((u >> 16) & 1u)) >> 16;
  return (unsigned short)r;
}
__device__ __forceinline__ float bf2f(unsigned short h) {
  return __uint_as_float(((unsigned)h) << 16);
}

__device__ __forceinline__ void gl_lds16(const void* g, void* l) {
  __builtin_amdgcn_global_load_lds(
      (const __attribute__((address_space(1))) void*)g,
      (__attribute__((address_space(3))) void*)l, 16, 0, 0);
}

// ---------------------------------------------------------------------------
// P0: split W (fp32 [o][c]) -> bf16 hi/lo (RNE). Whl: [br][hi|lo] ushort.
// ---------------------------------------------------------------------------
__global__ __launch_bounds__(256) void wsplit_k(
    const float* __restrict__ Wo, const float* __restrict__ Wsr,
    unsigned short* __restrict__ Whl) {
  const int br = blockIdx.y;
  const float* W = br ? Wsr : Wo;
  const int i = blockIdx.x * 256 + threadIdx.x;
  const float x = W[i];
  const unsigned short h = f2bf(x);
  unsigned short* dst = Whl + (size_t)br * 524288;
  dst[i] = h;
  dst[262144 + i] = f2bf(x - bf2f(h));
}

// ---------------------------------------------------------------------------
// K1 v4: MFMA GEMM  F[o][p] = sum_c W[o][c] * X[c][p]  (split-bf16 3-prod).
// Staging identical to round-5 (measured best). Wave tiling changed from
// 64x64 to 128m x 32n: each wave owns exclusive n-columns, so each X elem
// is hi/lo-converted ONCE per block (was twice) — conversion VALU halves.
// A-reads double (16 b128) but B-reads halve (16 b32): LDS-cycle neutral.
// ---------------------------------------------------------------------------
__global__ __launch_bounds__(256, 4) void mfma_conv_k(
    const unsigned short* __restrict__ Whl,
    const float* __restrict__ opt, const float* __restrict__ sar,
    float* __restrict__ F, int b0) {
  const int z = blockIdx.z;
  const int br = z & 1, bl = z >> 1;
  const unsigned short* Ah_g = Whl + (size_t)br * 524288;
  const unsigned short* Al_g = Ah_g + 262144;
  const float* Xb = (br ? sar : opt) + (size_t)(b0 + bl) * CHW;
  const int n0 = blockIdx.x * 128, m0 = blockIdx.y * 128;

  __shared__ unsigned short Ahs[128 * 32];  // 8 KB
  __shared__ unsigned short Als[128 * 32];  // 8 KB
  __shared__ float Xs[32 * 128];            // 16 KB

  const int tid = threadIdx.x;
  const int wave = tid >> 6, lane = tid & 63;
  const int wn = wave * 32;                 // exclusive 32 columns per wave

  f32x4 acc[8][2] = {};

  const int rl = lane >> 2;
  const int kcA = (((lane & 3) ^ ((lane >> 3) & 3)) * 8);

  const int brow_off = wave * 2 + (lane >> 5);  // 0..7
  const int bcol = (lane & 31) * 4;             // dest dword col

  const int fr = lane & 15;
  const int quad = lane >> 4;
  const int khA = ((quad ^ ((lane >> 1) & 3)) * 8);

  for (int k0 = 0; k0 < CCH; k0 += 32) {
    __syncthreads();
#pragma unroll
    for (int q = 0; q < 2; ++q) {
      const int rbase = wave * 32 + q * 16;
      const int r = rbase + rl;
      gl_lds16(Ah_g + (size_t)(m0 + r) * CCH + k0 + kcA, &Ahs[rbase * 32]);
      gl_lds16(Al_g + (size_t)(m0 + r) * CCH + k0 + kcA, &Als[rbase * 32]);
    }
#pragma unroll
    for (int t = 0; t < 4; ++t) {
      const int row = t * 8 + brow_off;
      const int srccol = (bcol + 128 - 8 * t) & 127;
      gl_lds16(&Xb[(size_t)(k0 + row) * HW + n0 + srccol],
               &Xs[t * 1024 + wave * 256]);
    }
    __syncthreads();

    // build both B fragment pairs (each elem converted once per block)
    bf16x8 bh[2], bl2[2];
#pragma unroll
    for (int j = 0; j < 2; ++j) {
      const int colj = (wn + j * 16 + fr + 8 * quad) & 127;
      float xv[8];
#pragma unroll
      for (int s = 0; s < 8; ++s) xv[s] = Xs[(quad * 8 + s) * 128 + colj];
      u32x4 hu, lu;
#pragma unroll
      for (int k = 0; k < 4; ++k) {
        const unsigned u0 = __float_as_uint(xv[2 * k]);
        const unsigned u1 = __float_as_uint(xv[2 * k + 1]);
        hu[k] = __builtin_amdgcn_perm(u1, u0, 0x07060302u);
        const float l0 = xv[2 * k] - __uint_as_float(u0 & 0xFFFF0000u);
        const float l1 = xv[2 * k + 1] - __uint_as_float(u1 & 0xFFFF0000u);
        lu[k] = __builtin_amdgcn_perm(__float_as_uint(l1), __float_as_uint(l0),
                                      0x07060302u);
      }
      bh[j] = __builtin_bit_cast(bf16x8, hu);
      bl2[j] = __builtin_bit_cast(bf16x8, lu);
    }

#pragma unroll
    for (int i = 0; i < 8; ++i) {
      const bf16x8 ah = *(const bf16x8*)&Ahs[(i * 16 + fr) * 32 + khA];
      const bf16x8 al = *(const bf16x8*)&Als[(i * 16 + fr) * 32 + khA];
#pragma unroll
      for (int j = 0; j < 2; ++j) {
        acc[i][j] = __builtin_amdgcn_mfma_f32_16x16x32_bf16(ah, bh[j], acc[i][j], 0, 0, 0);
        acc[i][j] = __builtin_amdgcn_mfma_f32_16x16x32_bf16(ah, bl2[j], acc[i][j], 0, 0, 0);
        acc[i][j] = __builtin_amdgcn_mfma_f32_16x16x32_bf16(al, bh[j], acc[i][j], 0, 0, 0);
      }
    }
  }

  float* Fb = F + (size_t)z * CHW;
  const int col = lane & 15, rq = (lane >> 4) * 4;
#pragma unroll
  for (int i = 0; i < 8; ++i)
#pragma unroll
    for (int j = 0; j < 2; ++j) {
      const int n = n0 + wn + j * 16 + col;
#pragma unroll
      for (int r = 0; r < 4; ++r) {
        const int m = m0 + i * 16 + rq + r;
        Fb[(size_t)m * HW + n] = acc[i][j][r];
      }
    }
}

// ---------------------------------------------------------------------------
// K2 v3: S = F^T F per (z,c) via split-bf16 MFMA. (unchanged from round 7)
// ---------------------------------------------------------------------------
#define FT_S 72
__global__ __launch_bounds__(256, 4) void gram_k(
    const float* __restrict__ F, float* __restrict__ S) {
  const size_t base = ((size_t)blockIdx.y * CCH + blockIdx.x) * HW;
  const float* Fc = F + base;
  float* Sc = S + base;

  __shared__ float Fs[64 * 64];                // 16 KB, unpadded
  __shared__ unsigned short FtH[64 * FT_S];
  __shared__ unsigned short FtL[64 * FT_S];

  const int tid = threadIdx.x;
  const int wave = tid >> 6, lane = tid & 63;

#pragma unroll
  for (int t = 0; t < 4; ++t) {
    const int off = (wave * 4 + t) * 256;
    gl_lds16(Fc + off + lane * 4, &Fs[off]);
  }
  __syncthreads();

  {
    const int w = lane;
    const int hc = wave * 16;
    unsigned short hb[16], lb[16];
#pragma unroll
    for (int k = 0; k < 16; ++k) {
      const float x = Fs[(hc + k) * 64 + w];
      const unsigned short h = f2bf(x);
      hb[k] = h;
      lb[k] = f2bf(x - bf2f(h));
    }
    unsigned short* dh = &FtH[w * FT_S + hc];
    unsigned short* dl = &FtL[w * FT_S + hc];
    *(uint4*)(dh + 0) = *(uint4*)&hb[0];
    *(uint4*)(dh + 8) = *(uint4*)&hb[8];
    *(uint4*)(dl + 0) = *(uint4*)&lb[0];
    *(uint4*)(dl + 8) = *(uint4*)&lb[8];
  }
  __syncthreads();

  const int wm = (wave >> 1) * 32, wn = (wave & 1) * 32;
  const int fr = lane & 15, kq = (lane >> 4) * 8;

  f32x4 acc[2][2] = {};
#pragma unroll
  for (int kcc = 0; kcc < 2; ++kcc) {
    bf16x8 ah[2], al[2], bh[2], bl[2];
#pragma unroll
    for (int i = 0; i < 2; ++i) {
      ah[i] = *(const bf16x8*)&FtH[(wm + i * 16 + fr) * FT_S + kcc * 32 + kq];
      al[i] = *(const bf16x8*)&FtL[(wm + i * 16 + fr) * FT_S + kcc * 32 + kq];
      bh[i] = *(const bf16x8*)&FtH[(wn + i * 16 + fr) * FT_S + kcc * 32 + kq];
      bl[i] = *(const bf16x8*)&FtL[(wn + i * 16 + fr) * FT_S + kcc * 32 + kq];
    }
#pragma unroll
    for (int i = 0; i < 2; ++i)
#pragma unroll
      for (int j = 0; j < 2; ++j) {
        acc[i][j] = __builtin_amdgcn_mfma_f32_16x16x32_bf16(ah[i], bh[j], acc[i][j], 0, 0, 0);
        acc[i][j] = __builtin_amdgcn_mfma_f32_16x16x32_bf16(ah[i], bl[j], acc[i][j], 0, 0, 0);
        acc[i][j] = __builtin_amdgcn_mfma_f32_16x16x32_bf16(al[i], bh[j], acc[i][j], 0, 0, 0);
      }
  }

  const int rq = (lane >> 4) * 4;
#pragma unroll
  for (int i = 0; i < 2; ++i)
#pragma unroll
    for (int j = 0; j < 2; ++j) {
      const int n = wn + j * 16 + fr;
#pragma unroll
      for (int r = 0; r < 4; ++r) {
        const int m = wm + i * 16 + rq + r;
        Sc[m * 64 + n] = acc[i][j][r];
      }
    }
}

// ---------------------------------------------------------------------------
// K3 v4: softmax over c (both branches) + hadamard + output. (unchanged)
// ---------------------------------------------------------------------------
__global__ __launch_bounds__(1024, 4) void softmax_fuse_k(
    const float* __restrict__ S, const float* __restrict__ Fbuf,
    float* __restrict__ Out) {
  const int i = blockIdx.x;   // 0..63
  const int b = blockIdx.y;
  const int tid = threadIdx.x;
  const int jl = (tid & 15) * 4;
  const int g = tid >> 4;     // 0..63 (8 c's each)

  const size_t rowO = (size_t)(b * 2) * CHW + (size_t)i * WDIM;
  const size_t rowS = rowO + CHW;

  float4 xoc[8], xsc[8];
  float mo[4], lo[4], ms[4], ls[4];
#pragma unroll
  for (int k = 0; k < 4; ++k) { mo[k] = -1e30f; ms[k] = -1e30f; lo[k] = 0.f; ls[k] = 0.f; }

#pragma unroll
  for (int cc = 0; cc < 8; ++cc) {
    const int c = g * 8 + cc;
    const size_t off = (size_t)c * HW + jl;
    xoc[cc] = *(const float4*)&S[rowO + off];
    xsc[cc] = *(const float4*)&S[rowS + off];
    mo[0] = fmaxf(mo[0], xoc[cc].x); mo[1] = fmaxf(mo[1], xoc[cc].y);
    mo[2] = fmaxf(mo[2], xoc[cc].z); mo[3] = fmaxf(mo[3], xoc[cc].w);
    ms[0] = fmaxf(ms[0], xsc[cc].x); ms[1] = fmaxf(ms[1], xsc[cc].y);
    ms[2] = fmaxf(ms[2], xsc[cc].z); ms[3] = fmaxf(ms[3], xsc[cc].w);
  }
#pragma unroll
  for (int cc = 0; cc < 8; ++cc) {
    lo[0] += __expf(xoc[cc].x - mo[0]); lo[1] += __expf(xoc[cc].y - mo[1]);
    lo[2] += __expf(xoc[cc].z - mo[2]); lo[3] += __expf(xoc[cc].w - mo[3]);
    ls[0] += __expf(xsc[cc].x - ms[0]); ls[1] += __expf(xsc[cc].y - ms[1]);
    ls[2] += __expf(xsc[cc].z - ms[2]); ls[3] += __expf(xsc[cc].w - ms[3]);
  }

  __shared__ float sm[2][64][64];
  __shared__ float sl[2][64][64];
  __shared__ float Mf[2][64];
  __shared__ float Li[2][64];

  *(float4*)&sm[0][g][jl] = make_float4(mo[0], mo[1], mo[2], mo[3]);
  *(float4*)&sl[0][g][jl] = make_float4(lo[0], lo[1], lo[2], lo[3]);
  *(float4*)&sm[1][g][jl] = make_float4(ms[0], ms[1], ms[2], ms[3]);
  *(float4*)&sl[1][g][jl] = make_float4(ls[0], ls[1], ls[2], ls[3]);
  __syncthreads();

  if (tid < 128) {
    const int br = tid >> 6, j = tid & 63;
    float M = -1e30f;
#pragma unroll 16
    for (int t = 0; t < 64; ++t) M = fmaxf(M, sm[br][t][j]);
    float L = 0.f;
#pragma unroll 16
    for (int t = 0; t < 64; ++t) L += sl[br][t][j] * __expf(sm[br][t][j] - M);
    Mf[br][j] = M;
    Li[br][j] = 1.f / L;
  }
  __syncthreads();

  float4 Mo4 = *(const float4*)&Mf[0][jl];
  float4 iLo4 = *(const float4*)&Li[0][jl];
  float4 Ms4 = *(const float4*)&Mf[1][jl];
  float4 iLs4 = *(const float4*)&Li[1][jl];
  float Mov[4] = {Mo4.x, Mo4.y, Mo4.z, Mo4.w};
  float iLov[4] = {iLo4.x, iLo4.y, iLo4.z, iLo4.w};
  float Msv[4] = {Ms4.x, Ms4.y, Ms4.z, Ms4.w};
  float iLsv[4] = {iLs4.x, iLs4.y, iLs4.z, iLs4.w};

#pragma unroll
  for (int cc = 0; cc < 8; ++cc) {
    const int c = g * 8 + cc;
    const size_t off = (size_t)c * HW + jl;
    float4 fo = *(const float4*)&Fbuf[rowO + off];
    float4 fs = *(const float4*)&Fbuf[rowS + off];
    float xov[4] = {xoc[cc].x, xoc[cc].y, xoc[cc].z, xoc[cc].w};
    float xsv[4] = {xsc[cc].x, xsc[cc].y, xsc[cc].z, xsc[cc].w};
    float fov[4] = {fo.x, fo.y, fo.z, fo.w};
    float fsv[4] = {fs.x, fs.y, fs.z, fs.w};
    float ov[4];
#pragma unroll
    for (int k = 0; k < 4; ++k) {
      const float ho = __expf(xov[k] - Mov[k]) * iLov[k];
      const float hs = __expf(xsv[k] - Msv[k]) * iLsv[k];
      float h2 = ho * hs;
      h2 *= h2;
      ov[k] = fov[k] * fsv[k] * h2;
    }
    *(float4*)&Out[(size_t)b * CHW + (size_t)c * HW + (size_t)i * WDIM + jl] =
        make_float4(ov[0], ov[1], ov[2], ov[3]);
  }
}

// ---------------------------------------------------------------------------
extern "C" void kernel_launch(void* const* d_in, const int* in_sizes, int n_in,
                              void* d_out, int out_size, void* d_ws, size_t ws_size,
                              hipStream_t stream) {
  const float* opt = (const float*)d_in[0];
  const float* sar = (const float*)d_in[1];
  const float* Wo  = (const float*)d_in[2];
  const float* Wsr = (const float*)d_in[3];
  float* out = (float*)d_out;

  // workspace: Whl | F | S
  unsigned short* Whl = (unsigned short*)d_ws;
  const size_t whlElems = 2u * 2u * 262144u;     // 2 MB
  const size_t perBl = 2 * CHW;                  // elems per batch (both br)
  const size_t perBlBytes = perBl * 8;           // F(4) + S(4)
  int bc = (int)((ws_size - whlElems * 2) / perBlBytes);
  if (bc < 1) bc = 1;
  if (bc > NBATCH) bc = NBATCH;
  const int passes = (NBATCH + bc - 1) / bc;
  const int nbp = (NBATCH + passes - 1) / passes;

  float* Fbuf = (float*)(Whl + whlElems);
  float* Sbuf = Fbuf + (size_t)bc * perBl;

  hipLaunchKernelGGL(wsplit_k, dim3(1024, 2), dim3(256), 0, stream, Wo, Wsr, Whl);

  for (int b0 = 0; b0 < NBATCH; b0 += nbp) {
    const int nb = (NBATCH - b0 < nbp) ? (NBATCH - b0) : nbp;

    hipLaunchKernelGGL(mfma_conv_k, dim3(32, 4, nb * 2), dim3(256), 0, stream,
                       Whl, opt, sar, Fbuf, b0);

    hipLaunchKernelGGL(gram_k, dim3(CCH, nb * 2), dim3(256), 0, stream,
                       Fbuf, Sbuf);

    hipLaunchKernelGGL(softmax_fuse_k, dim3(WDIM, nb), dim3(1024), 0, stream,
                       Sbuf, Fbuf, out + (size_t)b0 * CHW);
  }
}